// Round 17
// baseline (683.211 us; speedup 1.0000x reference)
//
#include <hip/hip_runtime.h>

#define BATCH 256
#define TLEN  512
#define DIN   64
#define HID   128
#define NOUT  40
#define SC    16
#define NCH   (TLEN / SC)   // 32 chunks
#define NPAIR (BATCH / 2)   // 128 batch pairs

typedef _Float16 f16x8 __attribute__((ext_vector_type(8)));
typedef float    f32x4 __attribute__((ext_vector_type(4)));

#define MFMA16(a, b, c) __builtin_amdgcn_mfma_f32_16x16x32_f16((a), (b), (c), 0, 0, 0)

// LDS-visibility barrier only: no vmcnt drain.
#define BARRIER() do {                                      \
    asm volatile("s_waitcnt lgkmcnt(0)" ::: "memory");      \
    __builtin_amdgcn_s_barrier();                           \
} while (0)

static __device__ __forceinline__ f16x8 pack8(float4 a, float4 b) {
    f16x8 v;
    v[0] = (_Float16)a.x; v[1] = (_Float16)a.y; v[2] = (_Float16)a.z; v[3] = (_Float16)a.w;
    v[4] = (_Float16)b.x; v[5] = (_Float16)b.y; v[6] = (_Float16)b.z; v[7] = (_Float16)b.w;
    return v;
}
static __device__ __forceinline__ float sig_(float x) {
    return __builtin_amdgcn_rcpf(1.0f + __expf(-x));
}
static __device__ __forceinline__ float tanh_(float x) {
    return fmaf(-2.0f, __builtin_amdgcn_rcpf(__expf(2.0f * x) + 1.0f), 1.0f);
}
static __device__ __forceinline__ f32x4 splat4(float v) { return (f32x4){v, v, v, v}; }

// Weight fragment loader; uses kernel-local `kg`. k = kt*32 + kg*8 + j.
#define LD8(base, g, K, kt) pack8(*(const float4*)((base) + (size_t)(g) * (K) + (kt) * 32 + kg * 8), \
                                  *(const float4*)((base) + (size_t)(g) * (K) + (kt) * 32 + kg * 8 + 4))

// One K-round of the h-recurrence: 8 chains (4 gates x 2 hid-halves).
#define HROUND(H, KT)                                                           \
    aA0 = MFMA16(H, WhA0_##KT, aA0); aA1 = MFMA16(H, WhA1_##KT, aA1);           \
    aA2 = MFMA16(H, WhA2_##KT, aA2); aA3 = MFMA16(H, WhA3_##KT, aA3);           \
    aB0 = MFMA16(H, WhB0_##KT, aB0); aB1 = MFMA16(H, WhB1_##KT, aB1);           \
    aB2 = MFMA16(H, WhB2_##KT, aB2); aB3 = MFMA16(H, WhB3_##KT, aB3);

// One LSTM cell: acc element E (0=batch0, 1=batch1), xi holds bias+input-proj.
#define CELL(A0v, A1v, A2v, A3v, E, XI, CC, HV)                                 \
    {                                                                           \
        float iv = sig_(A0v[E] + XI[0]), fv = sig_(A1v[E] + XI[1]);             \
        float gv = tanh_(A2v[E] + XI[2]), ov = sig_(A3v[E] + XI[3]);            \
        CC = fmaf(fv, CC, iv * gv);                                             \
        HV = ov * tanh_(CC);                                                    \
    }

// ====== Producer-consumer 2-layer LSTM, NB=2, disjoint CUs per layer ======
// 256 blocks x 256 thr (4 waves, 1 wave/SIMD, ~85KB LDS -> exactly 1 block/CU).
// Even blocks: layer0 for batch pair; odd blocks: layer1. Both layers advance
// concurrently on DIFFERENT CUs; handoff = global y0 slab + per-pair chunk flag
// (agent release/acquire). l0 never waits -> deadlock-free without co-residency.
// A-rows 0,1 = the two batches (junk rows 2-15 replicated, outputs ignored).
__global__ void __attribute__((amdgpu_flat_work_group_size(256, 256), amdgpu_waves_per_eu(1, 1)))
lstm_pipe(const float* __restrict__ x,
          const float* __restrict__ Wih0, const float* __restrict__ Whh0,
          const float* __restrict__ bih0, const float* __restrict__ bhh0,
          const float* __restrict__ Wih1, const float* __restrict__ Whh1,
          const float* __restrict__ bih1, const float* __restrict__ bhh1,
          const float* __restrict__ Wfc,  const float* __restrict__ bfc,
          _Float16* __restrict__ y0g, int* __restrict__ prod,
          float* __restrict__ out)
{
    const int role = blockIdx.x & 1;          // 0 = layer0, 1 = layer1
    const int pair = blockIdx.x >> 1;         // 0..127
    const int b0   = pair * 2, b1 = b0 + 1;
    const int tid  = threadIdx.x;
    const int lane = tid & 63, wave = tid >> 6;
    const int col  = lane & 15, kg = lane >> 4;
    const int hidA = wave * 32 + col;
    const int hidB = hidA + 16;

    __shared__ __align__(16) float    xacc[SC * 2 * HID * 4];   // 64 KB [tl][q][hid][4]
    __shared__ __align__(16) _Float16 h_lds[2][2][HID];         // [P][q][hid]
    __shared__ __align__(16) float    lds_pad[5120];            // 20 KB -> ~85 KB total
    if ((int)blockIdx.x < 0) out[0] = lds_pad[tid];             // keep pad (never true)

    const float* Whh = role ? Whh1 : Whh0;
    const float* Wih = role ? Wih1 : Wih0;
    const float* bi  = role ? bih1 : bih0;
    const float* bh  = role ? bhh1 : bhh0;

    // ---- held recurrent weights: 32 frags -> 128 AGPR ----
    f16x8 WhA0_0 = LD8(Whh, 0 * HID + hidA, HID, 0), WhA0_1 = LD8(Whh, 0 * HID + hidA, HID, 1);
    f16x8 WhA0_2 = LD8(Whh, 0 * HID + hidA, HID, 2), WhA0_3 = LD8(Whh, 0 * HID + hidA, HID, 3);
    f16x8 WhA1_0 = LD8(Whh, 1 * HID + hidA, HID, 0), WhA1_1 = LD8(Whh, 1 * HID + hidA, HID, 1);
    f16x8 WhA1_2 = LD8(Whh, 1 * HID + hidA, HID, 2), WhA1_3 = LD8(Whh, 1 * HID + hidA, HID, 3);
    f16x8 WhA2_0 = LD8(Whh, 2 * HID + hidA, HID, 0), WhA2_1 = LD8(Whh, 2 * HID + hidA, HID, 1);
    f16x8 WhA2_2 = LD8(Whh, 2 * HID + hidA, HID, 2), WhA2_3 = LD8(Whh, 2 * HID + hidA, HID, 3);
    f16x8 WhA3_0 = LD8(Whh, 3 * HID + hidA, HID, 0), WhA3_1 = LD8(Whh, 3 * HID + hidA, HID, 1);
    f16x8 WhA3_2 = LD8(Whh, 3 * HID + hidA, HID, 2), WhA3_3 = LD8(Whh, 3 * HID + hidA, HID, 3);
    f16x8 WhB0_0 = LD8(Whh, 0 * HID + hidB, HID, 0), WhB0_1 = LD8(Whh, 0 * HID + hidB, HID, 1);
    f16x8 WhB0_2 = LD8(Whh, 0 * HID + hidB, HID, 2), WhB0_3 = LD8(Whh, 0 * HID + hidB, HID, 3);
    f16x8 WhB1_0 = LD8(Whh, 1 * HID + hidB, HID, 0), WhB1_1 = LD8(Whh, 1 * HID + hidB, HID, 1);
    f16x8 WhB1_2 = LD8(Whh, 1 * HID + hidB, HID, 2), WhB1_3 = LD8(Whh, 1 * HID + hidB, HID, 3);
    f16x8 WhB2_0 = LD8(Whh, 2 * HID + hidB, HID, 0), WhB2_1 = LD8(Whh, 2 * HID + hidB, HID, 1);
    f16x8 WhB2_2 = LD8(Whh, 2 * HID + hidB, HID, 2), WhB2_3 = LD8(Whh, 2 * HID + hidB, HID, 3);
    f16x8 WhB3_0 = LD8(Whh, 3 * HID + hidB, HID, 0), WhB3_1 = LD8(Whh, 3 * HID + hidB, HID, 1);
    f16x8 WhB3_2 = LD8(Whh, 3 * HID + hidB, HID, 2), WhB3_3 = LD8(Whh, 3 * HID + hidB, HID, 3);
    asm("" : "+a"(WhA0_0), "+a"(WhA0_1), "+a"(WhA0_2), "+a"(WhA0_3),
             "+a"(WhA1_0), "+a"(WhA1_1), "+a"(WhA1_2), "+a"(WhA1_3));
    asm("" : "+a"(WhA2_0), "+a"(WhA2_1), "+a"(WhA2_2), "+a"(WhA2_3),
             "+a"(WhA3_0), "+a"(WhA3_1), "+a"(WhA3_2), "+a"(WhA3_3));
    asm("" : "+a"(WhB0_0), "+a"(WhB0_1), "+a"(WhB0_2), "+a"(WhB0_3),
             "+a"(WhB1_0), "+a"(WhB1_1), "+a"(WhB1_2), "+a"(WhB1_3));
    asm("" : "+a"(WhB2_0), "+a"(WhB2_1), "+a"(WhB2_2), "+a"(WhB2_3),
             "+a"(WhB3_0), "+a"(WhB3_1), "+a"(WhB3_2), "+a"(WhB3_3));

    // ---- Wx frags for l0 XPROJ (l1 loads dummies from Wih1, unused): 64 AGPR ----
    f16x8 WxA0_0 = LD8(Wih, 0 * HID + hidA, DIN, 0), WxA0_1 = LD8(Wih, 0 * HID + hidA, DIN, 1);
    f16x8 WxA1_0 = LD8(Wih, 1 * HID + hidA, DIN, 0), WxA1_1 = LD8(Wih, 1 * HID + hidA, DIN, 1);
    f16x8 WxA2_0 = LD8(Wih, 2 * HID + hidA, DIN, 0), WxA2_1 = LD8(Wih, 2 * HID + hidA, DIN, 1);
    f16x8 WxA3_0 = LD8(Wih, 3 * HID + hidA, DIN, 0), WxA3_1 = LD8(Wih, 3 * HID + hidA, DIN, 1);
    f16x8 WxB0_0 = LD8(Wih, 0 * HID + hidB, DIN, 0), WxB0_1 = LD8(Wih, 0 * HID + hidB, DIN, 1);
    f16x8 WxB1_0 = LD8(Wih, 1 * HID + hidB, DIN, 0), WxB1_1 = LD8(Wih, 1 * HID + hidB, DIN, 1);
    f16x8 WxB2_0 = LD8(Wih, 2 * HID + hidB, DIN, 0), WxB2_1 = LD8(Wih, 2 * HID + hidB, DIN, 1);
    f16x8 WxB3_0 = LD8(Wih, 3 * HID + hidB, DIN, 0), WxB3_1 = LD8(Wih, 3 * HID + hidB, DIN, 1);
    asm("" : "+a"(WxA0_0), "+a"(WxA0_1), "+a"(WxA1_0), "+a"(WxA1_1),
             "+a"(WxA2_0), "+a"(WxA2_1), "+a"(WxA3_0), "+a"(WxA3_1));
    asm("" : "+a"(WxB0_0), "+a"(WxB0_1), "+a"(WxB1_0), "+a"(WxB1_1),
             "+a"(WxB2_0), "+a"(WxB2_1), "+a"(WxB3_0), "+a"(WxB3_1));

    const float bsA0 = bi[0 * HID + hidA] + bh[0 * HID + hidA];
    const float bsA1 = bi[1 * HID + hidA] + bh[1 * HID + hidA];
    const float bsA2 = bi[2 * HID + hidA] + bh[2 * HID + hidA];
    const float bsA3 = bi[3 * HID + hidA] + bh[3 * HID + hidA];
    const float bsB0 = bi[0 * HID + hidB] + bh[0 * HID + hidB];
    const float bsB1 = bi[1 * HID + hidB] + bh[1 * HID + hidB];
    const float bsB2 = bi[2 * HID + hidB] + bh[2 * HID + hidB];
    const float bsB3 = bi[3 * HID + hidB] + bh[3 * HID + hidB];
    const f32x4 z4 = {0.f, 0.f, 0.f, 0.f};

    float ccA0 = 0.f, ccA1 = 0.f, ccB0 = 0.f, ccB1 = 0.f;
    float hvA0 = 0.f, hvA1 = 0.f, hvB0 = 0.f, hvB1 = 0.f;
    if (tid < HID) { h_lds[0][0][tid] = (_Float16)0.f; h_lds[0][1][tid] = (_Float16)0.f; }
    __syncthreads();

// ---- XPROJ (l0): 2 batch passes, A rows = 16 timesteps; bias in C-init ----
#define XPROJ(CB) do {                                                           \
    _Pragma("unroll")                                                            \
    for (int q = 0; q < 2; ++q) {                                                \
        const float* pa = x + ((size_t)(b0 + q) * TLEN + (CB) + col) * DIN + kg * 8; \
        f16x8 A0 = pack8(*(const float4*)pa,        *(const float4*)(pa + 4));   \
        f16x8 A1 = pack8(*(const float4*)(pa + 32), *(const float4*)(pa + 36));  \
        f32x4 gA0 = splat4(bsA0), gA1 = splat4(bsA1), gA2 = splat4(bsA2), gA3 = splat4(bsA3); \
        f32x4 gB0 = splat4(bsB0), gB1 = splat4(bsB1), gB2 = splat4(bsB2), gB3 = splat4(bsB3); \
        gA0 = MFMA16(A0, WxA0_0, gA0); gA1 = MFMA16(A0, WxA1_0, gA1);            \
        gA2 = MFMA16(A0, WxA2_0, gA2); gA3 = MFMA16(A0, WxA3_0, gA3);            \
        gB0 = MFMA16(A0, WxB0_0, gB0); gB1 = MFMA16(A0, WxB1_0, gB1);            \
        gB2 = MFMA16(A0, WxB2_0, gB2); gB3 = MFMA16(A0, WxB3_0, gB3);            \
        gA0 = MFMA16(A1, WxA0_1, gA0); gA1 = MFMA16(A1, WxA1_1, gA1);            \
        gA2 = MFMA16(A1, WxA2_1, gA2); gA3 = MFMA16(A1, WxA3_1, gA3);            \
        gB0 = MFMA16(A1, WxB0_1, gB0); gB1 = MFMA16(A1, WxB1_1, gB1);            \
        gB2 = MFMA16(A1, WxB2_1, gB2); gB3 = MFMA16(A1, WxB3_1, gB3);            \
        _Pragma("unroll") for (int r = 0; r < 4; ++r) {                          \
            const int tl = kg * 4 + r;                                           \
            *(float4*)&xacc[((tl * 2 + q) * HID + hidA) * 4] = make_float4(gA0[r], gA1[r], gA2[r], gA3[r]); \
            *(float4*)&xacc[((tl * 2 + q) * HID + hidB) * 4] = make_float4(gB0[r], gB1[r], gB2[r], gB3[r]); \
        }                                                                        \
    }                                                                            \
} while (0)

// ---- YPROJ (l1): Wy transient (32 frags), A from global y0 slab ----
#define YPROJ(CB) do {                                                           \
    f16x8 WyA0_0 = LD8(Wih, 0 * HID + hidA, HID, 0), WyA0_1 = LD8(Wih, 0 * HID + hidA, HID, 1); \
    f16x8 WyA0_2 = LD8(Wih, 0 * HID + hidA, HID, 2), WyA0_3 = LD8(Wih, 0 * HID + hidA, HID, 3); \
    f16x8 WyA1_0 = LD8(Wih, 1 * HID + hidA, HID, 0), WyA1_1 = LD8(Wih, 1 * HID + hidA, HID, 1); \
    f16x8 WyA1_2 = LD8(Wih, 1 * HID + hidA, HID, 2), WyA1_3 = LD8(Wih, 1 * HID + hidA, HID, 3); \
    f16x8 WyA2_0 = LD8(Wih, 2 * HID + hidA, HID, 0), WyA2_1 = LD8(Wih, 2 * HID + hidA, HID, 1); \
    f16x8 WyA2_2 = LD8(Wih, 2 * HID + hidA, HID, 2), WyA2_3 = LD8(Wih, 2 * HID + hidA, HID, 3); \
    f16x8 WyA3_0 = LD8(Wih, 3 * HID + hidA, HID, 0), WyA3_1 = LD8(Wih, 3 * HID + hidA, HID, 1); \
    f16x8 WyA3_2 = LD8(Wih, 3 * HID + hidA, HID, 2), WyA3_3 = LD8(Wih, 3 * HID + hidA, HID, 3); \
    f16x8 WyB0_0 = LD8(Wih, 0 * HID + hidB, HID, 0), WyB0_1 = LD8(Wih, 0 * HID + hidB, HID, 1); \
    f16x8 WyB0_2 = LD8(Wih, 0 * HID + hidB, HID, 2), WyB0_3 = LD8(Wih, 0 * HID + hidB, HID, 3); \
    f16x8 WyB1_0 = LD8(Wih, 1 * HID + hidB, HID, 0), WyB1_1 = LD8(Wih, 1 * HID + hidB, HID, 1); \
    f16x8 WyB1_2 = LD8(Wih, 1 * HID + hidB, HID, 2), WyB1_3 = LD8(Wih, 1 * HID + hidB, HID, 3); \
    f16x8 WyB2_0 = LD8(Wih, 2 * HID + hidB, HID, 0), WyB2_1 = LD8(Wih, 2 * HID + hidB, HID, 1); \
    f16x8 WyB2_2 = LD8(Wih, 2 * HID + hidB, HID, 2), WyB2_3 = LD8(Wih, 2 * HID + hidB, HID, 3); \
    f16x8 WyB3_0 = LD8(Wih, 3 * HID + hidB, HID, 0), WyB3_1 = LD8(Wih, 3 * HID + hidB, HID, 1); \
    f16x8 WyB3_2 = LD8(Wih, 3 * HID + hidB, HID, 2), WyB3_3 = LD8(Wih, 3 * HID + hidB, HID, 3); \
    _Pragma("unroll")                                                            \
    for (int q = 0; q < 2; ++q) {                                                \
        const _Float16* pa = y0g + ((size_t)(b0 + q) * TLEN + (CB) + col) * HID + kg * 8; \
        f16x8 A0 = *(const f16x8*)(pa);                                          \
        f16x8 A1 = *(const f16x8*)(pa + 32);                                     \
        f16x8 A2 = *(const f16x8*)(pa + 64);                                     \
        f16x8 A3 = *(const f16x8*)(pa + 96);                                     \
        f32x4 gA0 = splat4(bsA0), gA1 = splat4(bsA1), gA2 = splat4(bsA2), gA3 = splat4(bsA3); \
        f32x4 gB0 = splat4(bsB0), gB1 = splat4(bsB1), gB2 = splat4(bsB2), gB3 = splat4(bsB3); \
        gA0 = MFMA16(A0, WyA0_0, gA0); gA1 = MFMA16(A0, WyA1_0, gA1);            \
        gA2 = MFMA16(A0, WyA2_0, gA2); gA3 = MFMA16(A0, WyA3_0, gA3);            \
        gB0 = MFMA16(A0, WyB0_0, gB0); gB1 = MFMA16(A0, WyB1_0, gB1);            \
        gB2 = MFMA16(A0, WyB2_0, gB2); gB3 = MFMA16(A0, WyB3_0, gB3);            \
        gA0 = MFMA16(A1, WyA0_1, gA0); gA1 = MFMA16(A1, WyA1_1, gA1);            \
        gA2 = MFMA16(A1, WyA2_1, gA2); gA3 = MFMA16(A1, WyA3_1, gA3);            \
        gB0 = MFMA16(A1, WyB0_1, gB0); gB1 = MFMA16(A1, WyB1_1, gB1);            \
        gB2 = MFMA16(A1, WyB2_1, gB2); gB3 = MFMA16(A1, WyB3_1, gB3);            \
        gA0 = MFMA16(A2, WyA0_2, gA0); gA1 = MFMA16(A2, WyA1_2, gA1);            \
        gA2 = MFMA16(A2, WyA2_2, gA2); gA3 = MFMA16(A2, WyA3_2, gA3);            \
        gB0 = MFMA16(A2, WyB0_2, gB0); gB1 = MFMA16(A2, WyB1_2, gB1);            \
        gB2 = MFMA16(A2, WyB2_2, gB2); gB3 = MFMA16(A2, WyB3_2, gB3);            \
        gA0 = MFMA16(A3, WyA0_3, gA0); gA1 = MFMA16(A3, WyA1_3, gA1);            \
        gA2 = MFMA16(A3, WyA2_3, gA2); gA3 = MFMA16(A3, WyA3_3, gA3);            \
        gB0 = MFMA16(A3, WyB0_3, gB0); gB1 = MFMA16(A3, WyB1_3, gB1);            \
        gB2 = MFMA16(A3, WyB2_3, gB2); gB3 = MFMA16(A3, WyB3_3, gB3);            \
        _Pragma("unroll") for (int r = 0; r < 4; ++r) {                          \
            const int tl = kg * 4 + r;                                           \
            *(float4*)&xacc[((tl * 2 + q) * HID + hidA) * 4] = make_float4(gA0[r], gA1[r], gA2[r], gA3[r]); \
            *(float4*)&xacc[((tl * 2 + q) * HID + hidB) * 4] = make_float4(gB0[r], gB1[r], gB2[r], gB3[r]); \
        }                                                                        \
    }                                                                            \
} while (0)

// ---- steady step: 32 MFMA (8 chains of 4) + 4-cell ACT, one barrier ----
#define STEP_CORE(S, T, P) do {                                                  \
    const _Float16* hb = &h_lds[P][col & 1][0];                                  \
    f16x8 h0 = *(const f16x8*)(hb + kg * 8);                                     \
    f16x8 h1 = *(const f16x8*)(hb + 32 + kg * 8);                                \
    f16x8 h2 = *(const f16x8*)(hb + 64 + kg * 8);                                \
    f16x8 h3 = *(const f16x8*)(hb + 96 + kg * 8);                                \
    f32x4 aA0 = z4, aA1 = z4, aA2 = z4, aA3 = z4;                                \
    f32x4 aB0 = z4, aB1 = z4, aB2 = z4, aB3 = z4;                                \
    HROUND(h0, 0)                                                                \
    HROUND(h1, 1)                                                                \
    HROUND(h2, 2)                                                                \
    HROUND(h3, 3)                                                                \
    f32x4 xiA_0 = *(const f32x4*)&xacc[(((S) * 2 + 0) * HID + hidA) * 4];        \
    f32x4 xiA_1 = *(const f32x4*)&xacc[(((S) * 2 + 1) * HID + hidA) * 4];        \
    f32x4 xiB_0 = *(const f32x4*)&xacc[(((S) * 2 + 0) * HID + hidB) * 4];        \
    f32x4 xiB_1 = *(const f32x4*)&xacc[(((S) * 2 + 1) * HID + hidB) * 4];        \
    CELL(aA0, aA1, aA2, aA3, 0, xiA_0, ccA0, hvA0)                               \
    CELL(aA0, aA1, aA2, aA3, 1, xiA_1, ccA1, hvA1)                               \
    CELL(aB0, aB1, aB2, aB3, 0, xiB_0, ccB0, hvB0)                               \
    CELL(aB0, aB1, aB2, aB3, 1, xiB_1, ccB1, hvB1)                               \
    if (kg == 0) {                                                               \
        h_lds[(P) ^ 1][0][hidA] = (_Float16)hvA0;                                \
        h_lds[(P) ^ 1][1][hidA] = (_Float16)hvA1;                                \
        h_lds[(P) ^ 1][0][hidB] = (_Float16)hvB0;                                \
        h_lds[(P) ^ 1][1][hidB] = (_Float16)hvB1;                                \
        if (role == 0) {                                                         \
            y0g[((size_t)b0 * TLEN + (T)) * HID + hidA] = (_Float16)hvA0;        \
            y0g[((size_t)b0 * TLEN + (T)) * HID + hidB] = (_Float16)hvB0;        \
            y0g[((size_t)b1 * TLEN + (T)) * HID + hidA] = (_Float16)hvA1;        \
            y0g[((size_t)b1 * TLEN + (T)) * HID + hidB] = (_Float16)hvB1;        \
        }                                                                        \
    }                                                                            \
    BARRIER();                                                                   \
} while (0)

    for (int c = 0; c < NCH; ++c) {
        const int cb = c * SC;
        if (role == 0) {
            XPROJ(cb);
        } else {
            if (tid == 0) {
                while (__hip_atomic_load(&prod[pair], __ATOMIC_ACQUIRE,
                                         __HIP_MEMORY_SCOPE_AGENT) <= c)
                    __builtin_amdgcn_s_sleep(8);
            }
            __syncthreads();
            YPROJ(cb);
        }
        BARRIER();
        for (int s = 0; s < SC; s += 2) {
            STEP_CORE(s,     cb + s,     0);
            STEP_CORE(s + 1, cb + s + 1, 1);
        }
        if (role == 0) {
            __syncthreads();   // vmcnt drain: all this chunk's y0 stores complete
            if (tid == 0)
                __hip_atomic_store(&prod[pair], c + 1, __ATOMIC_RELEASE,
                                   __HIP_MEMORY_SCOPE_AGENT);
        }
    }

    // ---- fused FC on l1 blocks: out[b][o] = h1 · Wfc[o] + bfc[o] ----
    if (role == 1) {
        if (kg == 0) {
            xacc[0 * HID + hidA] = hvA0; xacc[1 * HID + hidA] = hvA1;
            xacc[0 * HID + hidB] = hvB0; xacc[1 * HID + hidB] = hvB1;
        }
        __syncthreads();
        if (tid < 2 * NOUT) {
            const int q = tid / NOUT, o = tid - q * NOUT;
            const float4* w   = (const float4*)(Wfc + (size_t)o * HID);
            const float4* hv4 = (const float4*)&xacc[q * HID];
            float acc = bfc[o];
            #pragma unroll
            for (int k = 0; k < HID / 4; ++k) {
                float4 wv = w[k]; float4 h4 = hv4[k];
                acc = fmaf(wv.x, h4.x, fmaf(wv.y, h4.y, fmaf(wv.z, h4.z, fmaf(wv.w, h4.w, acc))));
            }
            out[(size_t)(b0 + q) * NOUT + o] = acc;
        }
    }
}

extern "C" void kernel_launch(void* const* d_in, const int* in_sizes, int n_in,
                              void* d_out, int out_size, void* d_ws, size_t ws_size,
                              hipStream_t stream) {
    const float* x    = (const float*)d_in[0];
    const float* Wih0 = (const float*)d_in[1];
    const float* Whh0 = (const float*)d_in[2];
    const float* bih0 = (const float*)d_in[3];
    const float* bhh0 = (const float*)d_in[4];
    const float* Wih1 = (const float*)d_in[5];
    const float* Whh1 = (const float*)d_in[6];
    const float* bih1 = (const float*)d_in[7];
    const float* bhh1 = (const float*)d_in[8];
    const float* Wfc  = (const float*)d_in[9];
    const float* bfc  = (const float*)d_in[10];
    float* out = (float*)d_out;

    // ws: y0 slab [B][T][H] f16 (33.5 MB) | prod flags [NPAIR] int
    _Float16* y0g = (_Float16*)d_ws;
    int* prod = (int*)((char*)d_ws + (size_t)BATCH * TLEN * HID * sizeof(_Float16));

    hipMemsetAsync(prod, 0, NPAIR * sizeof(int), stream);
    lstm_pipe<<<2 * NPAIR, 256, 0, stream>>>(x, Wih0, Whh0, bih0, bhh0,
                                             Wih1, Whh1, bih1, bhh1,
                                             Wfc, bfc, y0g, prod, out);
}